// Round 10
// baseline (478.151 us; speedup 1.0000x reference)
//
#include <hip/hip_runtime.h>

// ---------------------------------------------------------------------------
// Controller: 4-layer LSTM stack + two heads.
// z = [x, h_prev[l], prev_layer]; K=1536 slice for ALL layers is one parallel
// GEMM (gemm_gates); only the K=1024 prev-layer slice is sequential.
//
// R5 changes (gates measured 266 TF, structure-bound; m97 ladder step):
//  * prep_all: ONE streaming kernel converts ALL weights to bf16
//    (Wg -> Wc, W_y -> Wyc, W_E -> WEc) and builds A0 (prep_a0 merged).
//  * gemm_gates / gemm_heads: staging via __builtin_amdgcn_global_load_lds
//    width=16 for BOTH operands (linear LDS, wave-uniform dest + lane*16),
//    no f32->bf16 repack in the GEMM, half the B bytes. Loop shape, grid,
//    XCD swizzle, epilogue identical to the R1-measured forms.
//  * seq_stream reads the converted Wc slice (conv_wseq dropped).
//  (R10 = R5 resubmit #5; R5-R9 benches were infra failures.)
//
// ws layout (bytes):
//   A0     @ 0         : bf16 [4][512][1536]    6,291,456
//   G      @ 6291456   : f32  [4][512][4096]   33,554,432  (bias folded)
//   hidden @ 39845888  : bf16 [512][4096]       4,194,304
//   Wc     @ 44040192  : bf16 [4][4096][2560]  83,886,080 (dead after seq3)
//     hpart @ 44040192 : f32  [8][512][768]    12,582,912 (aliases dead Wc)
//   Wyc    @ 127926272 : bf16 [512][4096]       4,194,304
//   WEc    @ 132120576 : bf16 [256][4096]       2,097,152
//   total 134,217,728
// ---------------------------------------------------------------------------

typedef short    shortx8  __attribute__((ext_vector_type(8)));
typedef float    floatx4  __attribute__((ext_vector_type(4)));
typedef float    floatx16 __attribute__((ext_vector_type(16)));

#define GLOAD16(SRC, DST)                                                    \
  __builtin_amdgcn_global_load_lds(                                          \
      (const __attribute__((address_space(1))) unsigned int*)(SRC),          \
      (__attribute__((address_space(3))) unsigned int*)(DST), 16, 0, 0)

__device__ __forceinline__ unsigned int f2bf1(float x) {
  unsigned int u = __float_as_uint(x);
  return (u + 0x7fffu + ((u >> 16) & 1u)) >> 16;   // RNE to bf16 bits
}
__device__ __forceinline__ unsigned int f2bf2(float lo, float hi) {
  return f2bf1(lo) | (f2bf1(hi) << 16);
}
__device__ __forceinline__ float sigm(float x) { return 1.f / (1.f + __expf(-x)); }
__device__ __forceinline__ float tanh_(float x) { return 1.f - 2.f / (__expf(2.f * x) + 1.f); }

// ---------------------------------------------------------------------------
// prep_all: blocks [0,22016): linear f32->bf16 copy-convert of Wg|W_y|W_E
// (45,088,768 elems, 8/thread, boundaries block-aligned). blocks [22016,
// 23552): A0[l][b][:] = bf16(x[b] ++ h_prev[l][b]).
// ---------------------------------------------------------------------------
__global__ __launch_bounds__(256) void prep_all(
    const float* __restrict__ x, const float* __restrict__ hp,
    const float* __restrict__ Wg, const float* __restrict__ Wy,
    const float* __restrict__ WE, unsigned short* __restrict__ A0,
    unsigned short* __restrict__ Wc, unsigned short* __restrict__ Wyc,
    unsigned short* __restrict__ WEc) {
  const int bid = blockIdx.x;
  if (bid < 22016) {
    const size_t i8 = ((size_t)bid * 256 + threadIdx.x) * 8;
    const float* s;
    unsigned short* d;
    if (i8 < 41943040u) { s = Wg + i8; d = Wc + i8; }
    else if (i8 < 44040192u) { s = Wy + (i8 - 41943040u); d = Wyc + (i8 - 41943040u); }
    else { s = WE + (i8 - 44040192u); d = WEc + (i8 - 44040192u); }
    const float4 v0 = *(const float4*)(s);
    const float4 v1 = *(const float4*)(s + 4);
    uint4 o;
    o.x = f2bf2(v0.x, v0.y); o.y = f2bf2(v0.z, v0.w);
    o.z = f2bf2(v1.x, v1.y); o.w = f2bf2(v1.z, v1.w);
    *(uint4*)(d) = o;
  } else {
    const int j   = (bid - 22016) * 256 + threadIdx.x;  // < 393216
    const int l   = j / 98304;
    const int rem = j - l * 98304;
    const int b   = rem / 192;
    const int kk  = (rem - b * 192) * 8;
    float v[8];
    if (kk < 512) {
      const float* s = x + (size_t)b * 512 + kk;
#pragma unroll
      for (int i = 0; i < 8; ++i) v[i] = s[i];
    } else {
      const float* s = hp + ((size_t)l * 512 + b) * 1024 + (kk - 512);
#pragma unroll
      for (int i = 0; i < 8; ++i) v[i] = s[i];
    }
    uint4 o;
    o.x = f2bf2(v[0], v[1]); o.y = f2bf2(v[2], v[3]);
    o.z = f2bf2(v[4], v[5]); o.w = f2bf2(v[6], v[7]);
    *(uint4*)(A0 + ((size_t)l * 512 + b) * 1536 + kk) = o;
  }
}

// ---------------------------------------------------------------------------
// gemm_gates: G[l][b][n] = bg[l][n] + sum_{k<1536} A0[l][b][k] * Wc[l][n][k]
// BM=BN=128 BK=64, 256 thr, dbuf LDS 64KB (2 blocks/CU), BOTH operands
// staged by global_load_lds width=16 (linear LDS, m97 structure).
// grid (4,32,4), XCD swizzle as R1.
// ---------------------------------------------------------------------------
__global__ __launch_bounds__(256, 2) void gemm_gates(
    const unsigned short* __restrict__ A0, const unsigned short* __restrict__ Wc,
    const float* __restrict__ bg, float* __restrict__ G) {
  __shared__ __align__(16) unsigned short As[2][128 * 64];
  __shared__ __align__(16) unsigned short Bs[2][128 * 64];
  const int tid = threadIdx.x, lane = tid & 63, wave = tid >> 6;
  const int raw   = blockIdx.x + 4 * (blockIdx.y + 32 * blockIdx.z); // 0..511
  const int xcd   = raw & 7, slot = raw >> 3;                        // slot 0..63
  const int nl    = (slot >> 2) * 8 + xcd;                           // 0..127
  const int mbase = (slot & 3) * 128;
  const int nbase = (nl & 31) * 128;
  const int l     = nl >> 5;
  const unsigned short* Ab = A0 + ((size_t)l * 512 + mbase) * 1536;
  const unsigned short* Bb = Wc + (size_t)l * 4096 * 2560 + (size_t)nbase * 2560;
  const int wv8 = wave * 8;
  const int lr  = lane >> 3;      // 0..7
  const int lc  = (lane & 7) * 8; // k-col in shorts

  auto stage = [&](int kt, int buf) {
    const int kg = kt * 64;
#pragma unroll
    for (int r = 0; r < 4; ++r)
      GLOAD16(Ab + (size_t)(wv8 + lr + r * 32) * 1536 + kg + lc,
              &As[buf][(wv8 + r * 32) * 64]);
#pragma unroll
    for (int r = 0; r < 4; ++r)
      GLOAD16(Bb + (size_t)(wv8 + lr + r * 32) * 2560 + kg + lc,
              &Bs[buf][(wv8 + r * 32) * 64]);
  };

  floatx16 acc[2][2];
#pragma unroll
  for (int a = 0; a < 2; ++a)
#pragma unroll
    for (int b2 = 0; b2 < 2; ++b2)
#pragma unroll
      for (int r = 0; r < 16; ++r) acc[a][b2][r] = 0.f;

  const int wm = (wave >> 1) * 64, wn = (wave & 1) * 64;
  auto compute = [&](int cb) {
#pragma unroll
    for (int ks = 0; ks < 4; ++ks) {
      const int gb = ks * 2 + (lane >> 5);
      shortx8 af[2], bfv[2];
#pragma unroll
      for (int sm = 0; sm < 2; ++sm)
        af[sm] = *(const shortx8*)(&As[cb][(wm + sm * 32 + (lane & 31)) * 64 + gb * 8]);
#pragma unroll
      for (int sn = 0; sn < 2; ++sn)
        bfv[sn] = *(const shortx8*)(&Bs[cb][(wn + sn * 32 + (lane & 31)) * 64 + gb * 8]);
#pragma unroll
      for (int sm = 0; sm < 2; ++sm)
#pragma unroll
        for (int sn = 0; sn < 2; ++sn)
          acc[sm][sn] = __builtin_amdgcn_mfma_f32_32x32x16_bf16(
              af[sm], bfv[sn], acc[sm][sn], 0, 0, 0);
    }
  };

  stage(0, 0);
  __syncthreads();
#pragma unroll 1
  for (int kt = 0; kt < 24; ++kt) {
    if (kt + 1 < 24) stage(kt + 1, (kt + 1) & 1);
    compute(kt & 1);
    __syncthreads();
  }

  const float* bgl = bg + (size_t)l * 4096;
  float* Gl = G + ((size_t)l * 512 + mbase) * 4096;
#pragma unroll
  for (int sm = 0; sm < 2; ++sm)
#pragma unroll
    for (int sn = 0; sn < 2; ++sn) {
      const int col = nbase + wn + sn * 32 + (lane & 31);
      const float bias = bgl[col];
#pragma unroll
      for (int r = 0; r < 16; ++r) {
        const int row = wm + sm * 32 + ((r & 3) + 8 * (r >> 2) + 4 * (lane >> 5));
        Gl[(size_t)row * 4096 + col] = acc[sm][sn][r] + bias;
      }
    }
}

// ---------------------------------------------------------------------------
// cell0: layer 0 has zero prev-layer input -> pure pointwise on G[0].
// ---------------------------------------------------------------------------
__global__ __launch_bounds__(256) void cell0(const float* __restrict__ G,
                                             const float* __restrict__ cp_l,
                                             unsigned short* __restrict__ hidden) {
  const int idx = (blockIdx.x * 256 + threadIdx.x) * 4;
  const int b = idx >> 10, h = idx & 1023;
  const float* g0 = G + (size_t)b * 4096;
  const float4 vi = *(const float4*)(g0 + h);
  const float4 vf = *(const float4*)(g0 + 1024 + h);
  const float4 vo = *(const float4*)(g0 + 2048 + h);
  const float4 vs = *(const float4*)(g0 + 3072 + h);
  const float4 cp = *(const float4*)(cp_l + (size_t)b * 1024 + h);
  const float gi[4] = {vi.x, vi.y, vi.z, vi.w};
  const float gf[4] = {vf.x, vf.y, vf.z, vf.w};
  const float go[4] = {vo.x, vo.y, vo.z, vo.w};
  const float gs[4] = {vs.x, vs.y, vs.z, vs.w};
  const float cc[4] = {cp.x, cp.y, cp.z, cp.w};
  float hn[4];
#pragma unroll
  for (int j = 0; j < 4; ++j) {
    const float c = sigm(gf[j]) * cc[j] + sigm(gi[j]) * tanh_(gs[j]);
    hn[j] = sigm(go[j]) * tanh_(c);
  }
  uint2 o;
  o.x = f2bf2(hn[0], hn[1]);
  o.y = f2bf2(hn[2], hn[3]);
  *(uint2*)(hidden + (size_t)b * 4096 + h) = o;
}

// ---------------------------------------------------------------------------
// seq_stream: wave-autonomous seq-layer GEMM + fused LSTM cell (R4 body).
// B operand read from converted Wc (row stride 2560, col offset 1536,
// gate offset 1024*2560 shorts). 512 blocks x 256 thr, no barriers, no LDS.
// ---------------------------------------------------------------------------
__global__ __launch_bounds__(256) void seq_stream(
    const unsigned short* __restrict__ hidden_ro,
    const unsigned short* __restrict__ Wc,
    const float* __restrict__ G, const float* __restrict__ c_prev,
    unsigned short* __restrict__ hidden_w, int l) {
  const int tid = threadIdx.x, lane = tid & 63, wv = tid >> 6;
  const int bid = blockIdx.x;            // 0..511
  const int x   = bid & 7;               // xcd
  const int mg  = (bid >> 3) & 7;        // m-group
  const int t   = bid >> 6;              // 0..7
  const int ht  = x * 8 + t;             // 0..63
  const int mt  = mg * 4 + wv;           // 0..31
  const int mb  = mt * 16, h0 = ht * 16;
  const int lrow = lane & 15, lg = lane >> 4;

  const unsigned short* Ab = hidden_ro + (size_t)(mb + lrow) * 4096
                             + (size_t)(l - 1) * 1024 + lg * 8;
  const unsigned short* Bb = Wc + (size_t)l * 4096 * 2560
                             + (size_t)(h0 + lrow) * 2560 + 1536 + lg * 8;

  // epilogue operands issued up front (independent of the K loop)
  const int brow = mb + lg * 4;
  const int hg   = h0 + lrow;
  float gvv[4][4];   // [gate][r]
  float cold[4];
#pragma unroll
  for (int r = 0; r < 4; ++r) {
    const float* Gb = G + ((size_t)l * 512 + brow + r) * 4096 + hg;
#pragma unroll
    for (int g = 0; g < 4; ++g) gvv[g][r] = Gb[g * 1024];
    cold[r] = c_prev[((size_t)l * 512 + brow + r) * 1024 + hg];
  }

  floatx4 acc0, acc1, acc2, acc3;
#pragma unroll
  for (int r = 0; r < 4; ++r) { acc0[r] = 0.f; acc1[r] = 0.f; acc2[r] = 0.f; acc3[r] = 0.f; }

  shortx8 a0, a1, a2, a3;
  shortx8 b00, b01, b02, b03;
  shortx8 b10, b11, b12, b13;
  shortx8 b20, b21, b22, b23;
  shortx8 b30, b31, b32, b33;

#define LD_SET(ai, b0_, b1_, b2_, b3_, kt)                                   \
  {                                                                          \
    const int ko = (kt) * 32;                                                \
    ai  = *(const shortx8*)(Ab + ko);                                        \
    b0_ = *(const shortx8*)(Bb + ko);                                        \
    b1_ = *(const shortx8*)(Bb + 2621440 + ko);                              \
    b2_ = *(const shortx8*)(Bb + 5242880 + ko);                              \
    b3_ = *(const shortx8*)(Bb + 7864320 + ko);                              \
  }
#define C_SET(ai, b0_, b1_, b2_, b3_)                                        \
  {                                                                          \
    acc0 = __builtin_amdgcn_mfma_f32_16x16x32_bf16(ai, b0_, acc0, 0, 0, 0);  \
    acc1 = __builtin_amdgcn_mfma_f32_16x16x32_bf16(ai, b1_, acc1, 0, 0, 0);  \
    acc2 = __builtin_amdgcn_mfma_f32_16x16x32_bf16(ai, b2_, acc2, 0, 0, 0);  \
    acc3 = __builtin_amdgcn_mfma_f32_16x16x32_bf16(ai, b3_, acc3, 0, 0, 0);  \
  }

  LD_SET(a0, b00, b01, b02, b03, 0)
  LD_SET(a1, b10, b11, b12, b13, 1)
  LD_SET(a2, b20, b21, b22, b23, 2)
  LD_SET(a3, b30, b31, b32, b33, 3)
#pragma unroll 1
  for (int kt4 = 0; kt4 < 8; ++kt4) {
    const int kt = kt4 * 4;
    C_SET(a0, b00, b01, b02, b03)
    if (kt + 4 < 32) LD_SET(a0, b00, b01, b02, b03, kt + 4)
    C_SET(a1, b10, b11, b12, b13)
    if (kt + 5 < 32) LD_SET(a1, b10, b11, b12, b13, kt + 5)
    C_SET(a2, b20, b21, b22, b23)
    if (kt + 6 < 32) LD_SET(a2, b20, b21, b22, b23, kt + 6)
    C_SET(a3, b30, b31, b32, b33)
    if (kt + 7 < 32) LD_SET(a3, b30, b31, b32, b33, kt + 7)
  }
#undef LD_SET
#undef C_SET

  // fused LSTM cell, fully in-register
#pragma unroll
  for (int r = 0; r < 4; ++r) {
    const float gi = acc0[r] + gvv[0][r];
    const float gf = acc1[r] + gvv[1][r];
    const float go = acc2[r] + gvv[2][r];
    const float gs = acc3[r] + gvv[3][r];
    const float c  = sigm(gf) * cold[r] + sigm(gi) * tanh_(gs);
    const float hn = sigm(go) * tanh_(c);
    hidden_w[(size_t)(brow + r) * 4096 + l * 1024 + hg] = (unsigned short)f2bf1(hn);
  }
}

// ---------------------------------------------------------------------------
// gemm_heads: split-K GEMM over hidden[512][4096] x bf16 [Wyc;WEc] -> hpart.
// BM=BN=128 BK=64, dbuf, global_load_lds staging both operands, grid
// (8 ksplit, 6 n, 4 m), XCD swizzle as R1.
// ---------------------------------------------------------------------------
__global__ __launch_bounds__(256, 2) void gemm_heads(
    const unsigned short* __restrict__ A, const unsigned short* __restrict__ Wyc,
    const unsigned short* __restrict__ WEc, float* __restrict__ Cp) {
  __shared__ __align__(16) unsigned short As[2][128 * 64];
  __shared__ __align__(16) unsigned short Bs[2][128 * 64];
  const int tid = threadIdx.x, lane = tid & 63, wave = tid >> 6;
  const int rawb = blockIdx.x + 8 * (blockIdx.y + 6 * blockIdx.z); // 0..191
  const int xcd  = rawb & 7, slot = rawb >> 3;  // slot 0..23
  const int pair = (slot >> 2) * 8 + xcd;       // 0..47 = (nt, ksplit)
  const int mbase  = (slot & 3) * 128;
  const int ksplit = pair & 7;
  const int nt     = pair >> 3;                 // 0..5
  const int nbase  = nt * 128;
  const unsigned short* Bb = (nt < 4) ? (Wyc + (size_t)nbase * 4096)
                                      : (WEc + (size_t)(nbase - 512) * 4096);
  const int k0 = ksplit * 512;
  const unsigned short* Ab = A + (size_t)mbase * 4096;
  const int wv8 = wave * 8;
  const int lr  = lane >> 3;
  const int lc  = (lane & 7) * 8;

  auto stage = [&](int kt, int buf) {
    const int kg = k0 + kt * 64;
#pragma unroll
    for (int r = 0; r < 4; ++r)
      GLOAD16(Ab + (size_t)(wv8 + lr + r * 32) * 4096 + kg + lc,
              &As[buf][(wv8 + r * 32) * 64]);
#pragma unroll
    for (int r = 0; r < 4; ++r)
      GLOAD16(Bb + (size_t)(wv8 + lr + r * 32) * 4096 + kg + lc,
              &Bs[buf][(wv8 + r * 32) * 64]);
  };

  floatx16 acc[2][2];
#pragma unroll
  for (int a = 0; a < 2; ++a)
#pragma unroll
    for (int b2 = 0; b2 < 2; ++b2)
#pragma unroll
      for (int r = 0; r < 16; ++r) acc[a][b2][r] = 0.f;
  const int wm = (wave >> 1) * 64, wn = (wave & 1) * 64;

  auto compute = [&](int cb) {
#pragma unroll
    for (int ks = 0; ks < 4; ++ks) {
      const int gb = ks * 2 + (lane >> 5);
      shortx8 af[2], bfv[2];
#pragma unroll
      for (int sm = 0; sm < 2; ++sm)
        af[sm] = *(const shortx8*)(&As[cb][(wm + sm * 32 + (lane & 31)) * 64 + gb * 8]);
#pragma unroll
      for (int sn = 0; sn < 2; ++sn)
        bfv[sn] = *(const shortx8*)(&Bs[cb][(wn + sn * 32 + (lane & 31)) * 64 + gb * 8]);
#pragma unroll
      for (int sm = 0; sm < 2; ++sm)
#pragma unroll
        for (int sn = 0; sn < 2; ++sn)
          acc[sm][sn] = __builtin_amdgcn_mfma_f32_32x32x16_bf16(
              af[sm], bfv[sn], acc[sm][sn], 0, 0, 0);
    }
  };

  stage(0, 0);
  __syncthreads();
#pragma unroll 1
  for (int kt = 0; kt < 8; ++kt) {
    if (kt + 1 < 8) stage(kt + 1, (kt + 1) & 1);
    compute(kt & 1);
    __syncthreads();
  }

  float* Co = Cp + (size_t)ksplit * 512 * 768;
#pragma unroll
  for (int sm = 0; sm < 2; ++sm)
#pragma unroll
    for (int sn = 0; sn < 2; ++sn) {
      const int col = nbase + wn + sn * 32 + (lane & 31);
#pragma unroll
      for (int r = 0; r < 16; ++r) {
        const int row = mbase + wm + sm * 32 +
                        ((r & 3) + 8 * (r >> 2) + 4 * (lane >> 5));
        Co[(size_t)row * 768 + col] = acc[sm][sn][r];
      }
    }
}

// ---------------------------------------------------------------------------
// head_reduce: sum 8 k-split partials + bias -> d_out.  grid (3,512) x 256
// ---------------------------------------------------------------------------
__global__ __launch_bounds__(256) void head_reduce(
    const float* __restrict__ hp, const float* __restrict__ b_y,
    const float* __restrict__ b_E, float* __restrict__ out) {
  const int n = blockIdx.x * 256 + threadIdx.x;  // 0..767
  const int b = blockIdx.y;
  float s = 0.f;
#pragma unroll
  for (int ks = 0; ks < 8; ++ks)
    s += hp[(size_t)ks * 512 * 768 + (size_t)b * 768 + n];
  if (n < 512)
    out[(size_t)b * 512 + n] = s + b_y[n];
  else
    out[(size_t)512 * 512 + (size_t)b * 256 + (n - 512)] = s + b_E[n - 512];
}

// ---------------------------------------------------------------------------
extern "C" void kernel_launch(void* const* d_in, const int* in_sizes, int n_in,
                              void* d_out, int out_size, void* d_ws, size_t ws_size,
                              hipStream_t stream) {
  const float* x      = (const float*)d_in[0];
  const float* h_prev = (const float*)d_in[1];
  const float* c_prev = (const float*)d_in[2];
  const float* Wg     = (const float*)d_in[3];
  const float* bg     = (const float*)d_in[4];
  const float* W_y    = (const float*)d_in[5];
  const float* b_y    = (const float*)d_in[6];
  const float* W_E    = (const float*)d_in[7];
  const float* b_E    = (const float*)d_in[8];

  char* ws = (char*)d_ws;
  unsigned short* A0     = (unsigned short*)(ws + 0);
  float*          G      = (float*)(ws + 6291456);
  unsigned short* hidden = (unsigned short*)(ws + 39845888);
  unsigned short* Wc     = (unsigned short*)(ws + 44040192);   // dead after seq3
  float*          hpart  = (float*)(ws + 44040192);            // aliases dead Wc
  unsigned short* Wyc    = (unsigned short*)(ws + 127926272);
  unsigned short* WEc    = (unsigned short*)(ws + 132120576);

  prep_all<<<dim3(23552), 256, 0, stream>>>(x, h_prev, Wg, W_y, W_E,
                                            A0, Wc, Wyc, WEc);
  gemm_gates<<<dim3(4, 32, 4), 256, 0, stream>>>(A0, Wc, bg, G);
  cell0<<<512, 256, 0, stream>>>(G, c_prev, hidden);
  for (int l = 1; l < 4; ++l)
    seq_stream<<<dim3(512), 256, 0, stream>>>(hidden, Wc, G, c_prev,
                                              hidden, l);
  gemm_heads<<<dim3(8, 6, 4), 256, 0, stream>>>(hidden, Wyc, WEc, hpart);
  head_reduce<<<dim3(3, 512), 256, 0, stream>>>(hpart, b_y, b_E, (float*)d_out);
}

// Round 12
// 402.190 us; speedup vs baseline: 1.1889x; 1.1889x over previous
//
#include <hip/hip_runtime.h>

// ---------------------------------------------------------------------------
// Controller: 4-layer LSTM stack + two heads.
// Restructured: z = [x, prev_time_h, prev_layer_h]; the K=1536 slice (x,h_prev)
// for ALL layers is one parallel GEMM (gemm_gates); only the K=1024
// prev-layer slice is sequential (gemm_seq_cell, LSTM cell fused in
// epilogue). Layer 0's prev contribution is exactly zero -> pure pointwise.
//
// R12: reverted byte-identical to the session-best measured kernel (404.9us).
// Session ladder: every intervention regressed (swizzle 420, 2-deep 445,
// seq_stream 460, gload_lds 478, coop-fusion FAIL) — this structure is the
// measured optimum; ~97us of the total is the harness workspace re-poison
// fill inside the timed window (fixed floor).
//
// ws layout (bytes):
//   A0     @ 0        : bf16 [4][512][1536]   6,291,456
//   G      @ 6291456  : f32  [4][512][4096]  33,554,432  (bias folded)
//   hidden @ 39845888 : bf16 [512][4096]      4,194,304
//   hpart  @ 44040192 : f32  [8][512][768]   12,582,912
// ---------------------------------------------------------------------------

typedef short    shortx8  __attribute__((ext_vector_type(8)));
typedef float    floatx16 __attribute__((ext_vector_type(16)));

__device__ __forceinline__ unsigned int f2bf1(float x) {
  unsigned int u = __float_as_uint(x);
  return (u + 0x7fffu + ((u >> 16) & 1u)) >> 16;   // RNE to bf16 bits
}
__device__ __forceinline__ unsigned int f2bf2(float lo, float hi) {
  return f2bf1(lo) | (f2bf1(hi) << 16);
}
__device__ __forceinline__ float sigm(float x) { return 1.f / (1.f + __expf(-x)); }
__device__ __forceinline__ float tanh_(float x) { return 1.f - 2.f / (__expf(2.f * x) + 1.f); }

// ---------------------------------------------------------------------------
// prep_a0: A0[l][b][0:1536] = bf16(x[b] ++ h_prev[l][b]).  grid (384,4) x 256
// ---------------------------------------------------------------------------
__global__ __launch_bounds__(256) void prep_a0(const float* __restrict__ x,
                                               const float* __restrict__ hp,
                                               unsigned short* __restrict__ A0) {
  const int l   = blockIdx.y;
  const int idx = blockIdx.x * 256 + threadIdx.x;   // < 512*192
  const int b   = idx / 192;
  const int kk  = (idx - b * 192) * 8;
  float v[8];
  if (kk < 512) {
    const float* s = x + (size_t)b * 512 + kk;
#pragma unroll
    for (int i = 0; i < 8; ++i) v[i] = s[i];
  } else {
    const float* s = hp + ((size_t)l * 512 + b) * 1024 + (kk - 512);
#pragma unroll
    for (int i = 0; i < 8; ++i) v[i] = s[i];
  }
  uint4 o;
  o.x = f2bf2(v[0], v[1]); o.y = f2bf2(v[2], v[3]);
  o.z = f2bf2(v[4], v[5]); o.w = f2bf2(v[6], v[7]);
  *(uint4*)(A0 + ((size_t)l * 512 + b) * 1536 + kk) = o;
}

// ---------------------------------------------------------------------------
// gemm_gates: G[l][b][n] = bg[l][n] + sum_{k<1536} A0[l][b][k] * Wg[l][n][k]
// BM=BN=128 BK=64, 256 thr (2x2 waves of 64x64), double-buffered LDS (64KB,
// 2 blocks/CU), register prefetch, one barrier per ktile. grid (4,32,4).
// ---------------------------------------------------------------------------
__global__ __launch_bounds__(256, 2) void gemm_gates(
    const unsigned short* __restrict__ A0, const float* __restrict__ Wg,
    const float* __restrict__ bg, float* __restrict__ G) {
  __shared__ __align__(16) unsigned short As[2][128 * 64];
  __shared__ __align__(16) unsigned short Bs[2][128 * 64];
  const int tid = threadIdx.x, lane = tid & 63, wave = tid >> 6;
  const int mbase = blockIdx.x * 128;
  const int nbase = blockIdx.y * 128;
  const int l     = blockIdx.z;
  const unsigned short* Ab = A0 + ((size_t)l * 512 + mbase) * 1536;
  const float*          Bb = Wg + (size_t)l * 4096 * 2560 + (size_t)nbase * 2560;
  const int arow = wave * 8 + (lane >> 3);
  const int akg  = lane & 7;

  uint4  apf[4];
  float4 bpf[8];
  auto loadT = [&](int kt) {
    const int kg = kt * 64;
#pragma unroll
    for (int r = 0; r < 4; ++r)
      apf[r] = *(const uint4*)(Ab + (size_t)(arow + r * 32) * 1536 + kg + akg * 8);
#pragma unroll
    for (int j = 0; j < 8; ++j) {
      const int idx = j * 256 + tid;
      bpf[j] = *(const float4*)(Bb + (size_t)(idx >> 4) * 2560 + kg + (idx & 15) * 4);
    }
  };
  auto storeT = [&](int buf) {
#pragma unroll
    for (int r = 0; r < 4; ++r) {
      const int row = arow + r * 32;
      *(uint4*)(&As[buf][row * 64 + ((akg ^ (row & 7)) * 8)]) = apf[r];
    }
#pragma unroll
    for (int j = 0; j < 8; ++j) {
      const int idx = j * 256 + tid;
      const int n = idx >> 4, kc = (idx & 15) * 4;
      uint2 pk;
      pk.x = f2bf2(bpf[j].x, bpf[j].y);
      pk.y = f2bf2(bpf[j].z, bpf[j].w);
      *(uint2*)(&Bs[buf][n * 64 + (((kc >> 3) ^ (n & 7)) * 8) + (kc & 4)]) = pk;
    }
  };

  floatx16 acc[2][2];
#pragma unroll
  for (int a = 0; a < 2; ++a)
#pragma unroll
    for (int b2 = 0; b2 < 2; ++b2)
#pragma unroll
      for (int r = 0; r < 16; ++r) acc[a][b2][r] = 0.f;

  const int wm = (wave >> 1) * 64, wn = (wave & 1) * 64;
  loadT(0);
  storeT(0);
  __syncthreads();
  for (int kt = 0; kt < 24; ++kt) {
    if (kt + 1 < 24) loadT(kt + 1);
    const int cb = kt & 1;
#pragma unroll
    for (int ks = 0; ks < 4; ++ks) {
      const int gb = ks * 2 + (lane >> 5);
      shortx8 af[2], bfv[2];
#pragma unroll
      for (int sm = 0; sm < 2; ++sm) {
        const int row = wm + sm * 32 + (lane & 31);
        af[sm] = *(const shortx8*)(&As[cb][row * 64 + ((gb ^ (row & 7)) * 8)]);
      }
#pragma unroll
      for (int sn = 0; sn < 2; ++sn) {
        const int row = wn + sn * 32 + (lane & 31);
        bfv[sn] = *(const shortx8*)(&Bs[cb][row * 64 + ((gb ^ (row & 7)) * 8)]);
      }
#pragma unroll
      for (int sm = 0; sm < 2; ++sm)
#pragma unroll
        for (int sn = 0; sn < 2; ++sn)
          acc[sm][sn] = __builtin_amdgcn_mfma_f32_32x32x16_bf16(
              af[sm], bfv[sn], acc[sm][sn], 0, 0, 0);
    }
    if (kt + 1 < 24) storeT((kt + 1) & 1);
    __syncthreads();
  }

  const float* bgl = bg + (size_t)l * 4096;
  float* Gl = G + ((size_t)l * 512 + mbase) * 4096;
#pragma unroll
  for (int sm = 0; sm < 2; ++sm)
#pragma unroll
    for (int sn = 0; sn < 2; ++sn) {
      const int col = nbase + wn + sn * 32 + (lane & 31);
      const float bias = bgl[col];
#pragma unroll
      for (int r = 0; r < 16; ++r) {
        const int row = wm + sm * 32 + ((r & 3) + 8 * (r >> 2) + 4 * (lane >> 5));
        Gl[(size_t)row * 4096 + col] = acc[sm][sn][r] + bias;
      }
    }
}

// ---------------------------------------------------------------------------
// cell0: layer 0 has zero prev-layer input -> pure pointwise on G[0].
// grid 512 x 256, 4 elems/thread.
// ---------------------------------------------------------------------------
__global__ __launch_bounds__(256) void cell0(const float* __restrict__ G,
                                             const float* __restrict__ cp_l,
                                             unsigned short* __restrict__ hidden) {
  const int idx = (blockIdx.x * 256 + threadIdx.x) * 4;
  const int b = idx >> 10, h = idx & 1023;
  const float* g0 = G + (size_t)b * 4096;
  const float4 vi = *(const float4*)(g0 + h);
  const float4 vf = *(const float4*)(g0 + 1024 + h);
  const float4 vo = *(const float4*)(g0 + 2048 + h);
  const float4 vs = *(const float4*)(g0 + 3072 + h);
  const float4 cp = *(const float4*)(cp_l + (size_t)b * 1024 + h);
  const float gi[4] = {vi.x, vi.y, vi.z, vi.w};
  const float gf[4] = {vf.x, vf.y, vf.z, vf.w};
  const float go[4] = {vo.x, vo.y, vo.z, vo.w};
  const float gs[4] = {vs.x, vs.y, vs.z, vs.w};
  const float cc[4] = {cp.x, cp.y, cp.z, cp.w};
  float hn[4];
#pragma unroll
  for (int j = 0; j < 4; ++j) {
    const float c = sigm(gf[j]) * cc[j] + sigm(gi[j]) * tanh_(gs[j]);
    hn[j] = sigm(go[j]) * tanh_(c);
  }
  uint2 o;
  o.x = f2bf2(hn[0], hn[1]);
  o.y = f2bf2(hn[2], hn[3]);
  *(uint2*)(hidden + (size_t)b * 4096 + h) = o;
}

// ---------------------------------------------------------------------------
// gemm_seq_cell: Gp = Wg[l][:,:,1536:2560] . h_{l-1}  (K=1024), then fused
// LSTM cell. Block = BM=128 rows x BN=64 cols where n_local = g*16+hh
// (4 gates x 16 h) -> epilogue holds all 4 gates for (b,hh), cell computed
// after an LDS transpose. 512 thr = 8 waves (4m x 2n of 32x32), dbuf LDS.
// grid (4 m, 64 h-tiles).
// ---------------------------------------------------------------------------
__global__ __launch_bounds__(512, 2) void gemm_seq_cell(
    const unsigned short* __restrict__ hidden_ro, const float* __restrict__ Wg,
    const float* __restrict__ G, const float* __restrict__ c_prev,
    unsigned short* __restrict__ hidden_w, int l) {
  __shared__ __align__(16) unsigned char raw[49152];
  unsigned short* As = (unsigned short*)raw;            // 2 x 16384 B
  unsigned short* Bs = (unsigned short*)(raw + 32768);  // 2 x  8192 B
  float*          Gex = (float*)raw;                    // 33280 B (aliased)
  const int tid = threadIdx.x, lane = tid & 63, wave = tid >> 6;
  const int mbase = blockIdx.x * 128;
  const int h0    = blockIdx.y * 16;
  const unsigned short* Ab = hidden_ro + (size_t)(l - 1) * 1024;  // lda 4096
  const float*          Bl = Wg + (size_t)l * 4096 * 2560 + 1536; // lda 2560

  uint4  apf[2];
  float4 bpf[2];
  auto loadT = [&](int kt) {
    const int kg = kt * 64;
#pragma unroll
    for (int r = 0; r < 2; ++r) {
      const int row = (tid >> 3) + r * 64;
      apf[r] = *(const uint4*)(Ab + (size_t)(mbase + row) * 4096 + kg + (tid & 7) * 8);
    }
#pragma unroll
    for (int j = 0; j < 2; ++j) {
      const int idx = j * 512 + tid;
      const int nl = idx >> 4, kc = (idx & 15) * 4;
      const int grow = (nl >> 4) * 1024 + h0 + (nl & 15);
      bpf[j] = *(const float4*)(Bl + (size_t)grow * 2560 + kg + kc);
    }
  };
  auto storeT = [&](int buf) {
#pragma unroll
    for (int r = 0; r < 2; ++r) {
      const int row = (tid >> 3) + r * 64;
      *(uint4*)(&As[buf * 8192 + row * 64 + (((tid & 7) ^ (row & 7)) * 8)]) = apf[r];
    }
#pragma unroll
    for (int j = 0; j < 2; ++j) {
      const int idx = j * 512 + tid;
      const int nl = idx >> 4, kc = (idx & 15) * 4;
      uint2 pk;
      pk.x = f2bf2(bpf[j].x, bpf[j].y);
      pk.y = f2bf2(bpf[j].z, bpf[j].w);
      *(uint2*)(&Bs[buf * 4096 + nl * 64 + (((kc >> 3) ^ (nl & 7)) * 8) + (kc & 4)]) = pk;
    }
  };

  floatx16 acc;
#pragma unroll
  for (int r = 0; r < 16; ++r) acc[r] = 0.f;
  const int wm = (wave & 3) * 32, wn = (wave >> 2) * 32;

  loadT(0);
  storeT(0);
  __syncthreads();
  for (int kt = 0; kt < 16; ++kt) {
    if (kt + 1 < 16) loadT(kt + 1);
    const int cb = kt & 1;
    const int rowa = wm + (lane & 31);
    const int rowb = wn + (lane & 31);
#pragma unroll
    for (int ks = 0; ks < 4; ++ks) {
      const int gb = ks * 2 + (lane >> 5);
      const shortx8 af = *(const shortx8*)(&As[cb * 8192 + rowa * 64 + ((gb ^ (rowa & 7)) * 8)]);
      const shortx8 bfv = *(const shortx8*)(&Bs[cb * 4096 + rowb * 64 + ((gb ^ (rowb & 7)) * 8)]);
      acc = __builtin_amdgcn_mfma_f32_32x32x16_bf16(af, bfv, acc, 0, 0, 0);
    }
    if (kt + 1 < 16) storeT((kt + 1) & 1);
    __syncthreads();
  }

  // acc -> LDS (layout [b][n_local], pad 65)
  {
    const int col = wn + (lane & 31);
#pragma unroll
    for (int r = 0; r < 16; ++r) {
      const int row = wm + ((r & 3) + 8 * (r >> 2) + 4 * (lane >> 5));
      Gex[row * 65 + col] = acc[r];
    }
  }
  __syncthreads();

  // fused LSTM cell: 4 cells/thread over 128 b x 16 hh
  const int hh = tid & 15, q = tid >> 4;   // q in 0..31
#pragma unroll
  for (int bi = 0; bi < 4; ++bi) {
    const int bl = bi * 32 + q;
    const int b  = mbase + bl;
    const int hg = h0 + hh;
    const float* Gb = G + ((size_t)l * 512 + b) * 4096;
    float gv[4];
#pragma unroll
    for (int g = 0; g < 4; ++g)
      gv[g] = Gex[bl * 65 + g * 16 + hh] + Gb[g * 1024 + hg];
    const float c_old = c_prev[((size_t)l * 512 + b) * 1024 + hg];
    const float c  = sigm(gv[1]) * c_old + sigm(gv[0]) * tanh_(gv[3]);
    const float hn = sigm(gv[2]) * tanh_(c);
    hidden_w[(size_t)b * 4096 + l * 1024 + hg] = (unsigned short)f2bf1(hn);
  }
}

// ---------------------------------------------------------------------------
// gemm_heads: split-K GEMM over hidden[512][4096] x [W_y;W_E] -> partials.
// BM=BN=128 BK=64, dbuf, grid (8 ksplit, 6 n, 4 m), K=512 per split.
// ---------------------------------------------------------------------------
__global__ __launch_bounds__(256) void gemm_heads(
    const unsigned short* __restrict__ A, const float* __restrict__ Wy,
    const float* __restrict__ WE, float* __restrict__ Cp) {
  __shared__ __align__(16) unsigned short As[2][128 * 64];
  __shared__ __align__(16) unsigned short Bs[2][128 * 64];
  const int tid = threadIdx.x, lane = tid & 63, wave = tid >> 6;
  const int mbase = blockIdx.z * 128;
  const int nt    = blockIdx.y;
  const int nbase = nt * 128;
  const float* Bb = (nt < 4) ? (Wy + (size_t)nbase * 4096)
                             : (WE + (size_t)(nbase - 512) * 4096);
  const int k0 = blockIdx.x * 512;
  const unsigned short* Ab = A + (size_t)mbase * 4096;
  const int arow = wave * 8 + (lane >> 3);
  const int akg  = lane & 7;

  uint4  apf[4];
  float4 bpf[8];
  auto loadT = [&](int kt) {
    const int kg = k0 + kt * 64;
#pragma unroll
    for (int r = 0; r < 4; ++r)
      apf[r] = *(const uint4*)(Ab + (size_t)(arow + r * 32) * 4096 + kg + akg * 8);
#pragma unroll
    for (int j = 0; j < 8; ++j) {
      const int idx = j * 256 + tid;
      bpf[j] = *(const float4*)(Bb + (size_t)(idx >> 4) * 4096 + kg + (idx & 15) * 4);
    }
  };
  auto storeT = [&](int buf) {
#pragma unroll
    for (int r = 0; r < 4; ++r) {
      const int row = arow + r * 32;
      *(uint4*)(&As[buf][row * 64 + ((akg ^ (row & 7)) * 8)]) = apf[r];
    }
#pragma unroll
    for (int j = 0; j < 8; ++j) {
      const int idx = j * 256 + tid;
      const int n = idx >> 4, kc = (idx & 15) * 4;
      uint2 pk;
      pk.x = f2bf2(bpf[j].x, bpf[j].y);
      pk.y = f2bf2(bpf[j].z, bpf[j].w);
      *(uint2*)(&Bs[buf][n * 64 + (((kc >> 3) ^ (n & 7)) * 8) + (kc & 4)]) = pk;
    }
  };

  floatx16 acc[2][2];
#pragma unroll
  for (int a = 0; a < 2; ++a)
#pragma unroll
    for (int b2 = 0; b2 < 2; ++b2)
#pragma unroll
      for (int r = 0; r < 16; ++r) acc[a][b2][r] = 0.f;
  const int wm = (wave >> 1) * 64, wn = (wave & 1) * 64;

  loadT(0);
  storeT(0);
  __syncthreads();
  for (int kt = 0; kt < 8; ++kt) {
    if (kt + 1 < 8) loadT(kt + 1);
    const int cb = kt & 1;
#pragma unroll
    for (int ks = 0; ks < 4; ++ks) {
      const int gb = ks * 2 + (lane >> 5);
      shortx8 af[2], bfv[2];
#pragma unroll
      for (int sm = 0; sm < 2; ++sm) {
        const int row = wm + sm * 32 + (lane & 31);
        af[sm] = *(const shortx8*)(&As[cb][row * 64 + ((gb ^ (row & 7)) * 8)]);
      }
#pragma unroll
      for (int sn = 0; sn < 2; ++sn) {
        const int row = wn + sn * 32 + (lane & 31);
        bfv[sn] = *(const shortx8*)(&Bs[cb][row * 64 + ((gb ^ (row & 7)) * 8)]);
      }
#pragma unroll
      for (int sm = 0; sm < 2; ++sm)
#pragma unroll
        for (int sn = 0; sn < 2; ++sn)
          acc[sm][sn] = __builtin_amdgcn_mfma_f32_32x32x16_bf16(
              af[sm], bfv[sn], acc[sm][sn], 0, 0, 0);
    }
    if (kt + 1 < 8) storeT((kt + 1) & 1);
    __syncthreads();
  }

  float* Co = Cp + (size_t)blockIdx.x * 512 * 768;
#pragma unroll
  for (int sm = 0; sm < 2; ++sm)
#pragma unroll
    for (int sn = 0; sn < 2; ++sn) {
      const int col = nbase + wn + sn * 32 + (lane & 31);
#pragma unroll
      for (int r = 0; r < 16; ++r) {
        const int row = mbase + wm + sm * 32 +
                        ((r & 3) + 8 * (r >> 2) + 4 * (lane >> 5));
        Co[(size_t)row * 768 + col] = acc[sm][sn][r];
      }
    }
}

// ---------------------------------------------------------------------------
// head_reduce: sum 8 k-split partials + bias -> d_out.  grid (3,512) x 256
// ---------------------------------------------------------------------------
__global__ __launch_bounds__(256) void head_reduce(
    const float* __restrict__ hp, const float* __restrict__ b_y,
    const float* __restrict__ b_E, float* __restrict__ out) {
  const int n = blockIdx.x * 256 + threadIdx.x;  // 0..767
  const int b = blockIdx.y;
  float s = 0.f;
#pragma unroll
  for (int ks = 0; ks < 8; ++ks)
    s += hp[(size_t)ks * 512 * 768 + (size_t)b * 768 + n];
  if (n < 512)
    out[(size_t)b * 512 + n] = s + b_y[n];
  else
    out[(size_t)512 * 512 + (size_t)b * 256 + (n - 512)] = s + b_E[n - 512];
}

// ---------------------------------------------------------------------------
extern "C" void kernel_launch(void* const* d_in, const int* in_sizes, int n_in,
                              void* d_out, int out_size, void* d_ws, size_t ws_size,
                              hipStream_t stream) {
  const float* x      = (const float*)d_in[0];
  const float* h_prev = (const float*)d_in[1];
  const float* c_prev = (const float*)d_in[2];
  const float* Wg     = (const float*)d_in[3];
  const float* bg     = (const float*)d_in[4];
  const float* W_y    = (const float*)d_in[5];
  const float* b_y    = (const float*)d_in[6];
  const float* W_E    = (const float*)d_in[7];
  const float* b_E    = (const float*)d_in[8];

  char* ws = (char*)d_ws;
  unsigned short* A0     = (unsigned short*)(ws + 0);
  float*          G      = (float*)(ws + 6291456);
  unsigned short* hidden = (unsigned short*)(ws + 39845888);
  float*          hpart  = (float*)(ws + 44040192);

  prep_a0<<<dim3(384, 4), 256, 0, stream>>>(x, h_prev, A0);
  gemm_gates<<<dim3(4, 32, 4), 256, 0, stream>>>(A0, Wg, bg, G);
  cell0<<<512, 256, 0, stream>>>(G, c_prev, hidden);
  for (int l = 1; l < 4; ++l)
    gemm_seq_cell<<<dim3(4, 64), 512, 0, stream>>>(hidden, Wg, G, c_prev,
                                                   hidden, l);
  gemm_heads<<<dim3(8, 6, 4), 256, 0, stream>>>(hidden, W_y, W_E, hpart);
  head_reduce<<<dim3(3, 512), 256, 0, stream>>>(hpart, b_y, b_E, (float*)d_out);
}